// Round 31
// baseline (26.513 us; speedup 1.0000x reference)
//
#include <hip/hip_runtime.h>

// L=32768, N=32, E=H=1, BS=256 -> 4096 rank-1 softmax problems:
//   out_i = sum_j 2^(a'_i k_j) v_j / sum_j 2^(a'_i k_j),  a' = (wq q + bq) log2e.
// No max-subtraction (f32-safe, scale-invariant; validated R5-R30).
//
// R31 = R30 (17.8us, fused) + 2-wave-per-problem split to break the 16
// waves/CU cap (4096 waves was the invariant; splits give 8192 waves,
// 2048 WGs x 18KB LDS -> 8 WGs/CU = 32 waves/CU):
//  - each wave sorts ITS OWN half (128 elems) independently -- fixes R24's
//    idle-wave flaw; global kmn/kmx via one meta exchange.
//  - moments additive across halves (permutation-invariant); summed inline
//    in the row loop (12 reads + 6 adds per segment).
//  - per-wave moment scan and row loop HALVE (2 rows/lane).
//  - 3 barriers total (stage, minmax-meta, moments).

#define LL    32768
#define NN    32
#define BSZ   256
#define NBLK  (LL / BSZ)
#define NSEG  8
#define LOG2E 1.4426950408889634f
#define LN2   0.6931471805599453f

typedef float v2f __attribute__((ext_vector_type(2)));

// deg-10 Horner: coefficients c0..c10 = {f0.xyzw, f1.xyzw, f2.xyz}
__device__ __forceinline__ v2f horner10(v2f u, float4 f0, float4 f1, float4 f2) {
    v2f h = {f2.z, f2.z};
    h = __builtin_elementwise_fma(h, u, (v2f){f2.y, f2.y});
    h = __builtin_elementwise_fma(h, u, (v2f){f2.x, f2.x});
    h = __builtin_elementwise_fma(h, u, (v2f){f1.w, f1.w});
    h = __builtin_elementwise_fma(h, u, (v2f){f1.z, f1.z});
    h = __builtin_elementwise_fma(h, u, (v2f){f1.y, f1.y});
    h = __builtin_elementwise_fma(h, u, (v2f){f1.x, f1.x});
    h = __builtin_elementwise_fma(h, u, (v2f){f0.w, f0.w});
    h = __builtin_elementwise_fma(h, u, (v2f){f0.z, f0.z});
    h = __builtin_elementwise_fma(h, u, (v2f){f0.y, f0.y});
    h = __builtin_elementwise_fma(h, u, (v2f){f0.x, f0.x});
    return h;
}

__global__ __launch_bounds__(256) void BlockCrossAttn_kernel(
    const float* __restrict__ q_in, const float* __restrict__ k_in,
    const float* __restrict__ v_in,
    const float* __restrict__ ipw,  const float* __restrict__ ipb,
    const float* __restrict__ opw,  const float* __restrict__ opb,
    float* __restrict__ out)
{
    const int t    = threadIdx.x;        // 0..255
    const int lane = t & 63;
    const int w    = t >> 6;             // wave 0..3
    const int p    = w >> 1;             // problem 0/1 within WG
    const int h    = w & 1;              // half 0/1 (rows h*128..+127)
    const int g    = blockIdx.x;         // 0..2047
    const int blk  = g & 127;            // XCD-aware: siblings same XCD
    const int n0   = (g >> 7) << 1;      // 0,2,...,30

    __shared__ alignas(16) float  sA[2][BSZ];      // staged per problem
    __shared__ alignas(16) float  sK[2][BSZ];
    __shared__ alignas(16) float  sV[2][BSZ];
    __shared__ alignas(16) float2 skv[2][BSZ];     // sorted, per half-region
    __shared__ alignas(16) float  momH[2][2][NSEG][24]; // [prob][half]
    __shared__ int   hist[2][2][128];
    __shared__ float metaMn[4], metaMx[4];

    // ---- cooperative staging: thread t = row t, 2 batches n0..n0+1 ----
    {
        const float wq = ipw[0], wk = ipw[1], wv = ipw[2];
        const float bq = ipb[0], bk = ipb[1], bv = ipb[2];
        const int f = (blk * BSZ + t) * NN + n0;   // 8B aligned (n0 even)
        const float2 q2 = *reinterpret_cast<const float2*>(q_in + f);
        const float2 k2 = *reinterpret_cast<const float2*>(k_in + f);
        const float2 v2 = *reinterpret_cast<const float2*>(v_in + f);
        sA[0][t] = fmaf(q2.x, wq, bq) * LOG2E;
        sA[1][t] = fmaf(q2.y, wq, bq) * LOG2E;
        sK[0][t] = fmaf(k2.x, wk, bk);
        sK[1][t] = fmaf(k2.y, wk, bk);
        sV[0][t] = fmaf(v2.x, wv, bv);
        sV[1][t] = fmaf(v2.y, wv, bv);
    }
    __syncthreads();   // barrier 1: staging visible

    // ---- own-half data: lane owns rows h*128 + 2*lane + {0,1} ----
    const int rbase = h * 128 + 2 * lane;
    const float k0 = sK[p][rbase], k1 = sK[p][rbase + 1];
    const float v0 = sV[p][rbase], v1 = sV[p][rbase + 1];
    const float a0 = sA[p][rbase], a1 = sA[p][rbase + 1];

    // own-half kmin/kmax -> meta exchange -> global
    {
        float mn = fminf(k0, k1), mx = fmaxf(k0, k1);
        #pragma unroll
        for (int off = 32; off >= 1; off >>= 1) {
            mn = fminf(mn, __shfl_xor(mn, off));
            mx = fmaxf(mx, __shfl_xor(mx, off));
        }
        if (lane == 0) { metaMn[w] = mn; metaMx[w] = mx; }
    }
    __syncthreads();   // barrier 2: meta visible
    const float kmn = fminf(metaMn[2 * p], metaMn[2 * p + 1]);
    const float kmx = fmaxf(metaMx[2 * p], metaMx[2 * p + 1]);
    const float rng  = kmx - kmn;
    const float binv = (rng > 0.f) ? (127.99f / rng) : 0.f;
    const float segw = rng * (1.0f / NSEG);

    // ---- per-half counting sort (wave-private, no barriers) ----
    hist[p][h][lane]      = 0;
    hist[p][h][lane + 64] = 0;

    int b0 = (int)((k0 - kmn) * binv);
    int b1 = (int)((k1 - kmn) * binv);
    b0 = (b0 < 0) ? 0 : ((b0 > 127) ? 127 : b0);
    b1 = (b1 < 0) ? 0 : ((b1 > 127) ? 127 : b1);
    atomicAdd(&hist[p][h][b0], 1);       // wave-private, lane-ordered
    atomicAdd(&hist[p][h][b1], 1);

    {
        const int c0 = hist[p][h][lane];
        const int c1 = hist[p][h][lane + 64];
        int i0 = c0, i1 = c1;
        #pragma unroll
        for (int off = 1; off <= 32; off <<= 1) {
            const int t0 = __shfl_up(i0, off);
            const int t1 = __shfl_up(i1, off);
            if (lane >= off) { i0 += t0; i1 += t1; }
        }
        const int tot0 = __shfl(i0, 63);
        hist[p][h][lane]      = i0 - c0;  // exclusive starts
        hist[p][h][lane + 64] = i1 - c1 + tot0;
    }

    {
        const int s0 = atomicAdd(&hist[p][h][b0], 1);
        skv[p][h * 128 + s0] = make_float2(k0, v0);
        const int s1 = atomicAdd(&hist[p][h][b1], 1);
        skv[p][h * 128 + s1] = make_float2(k1, v1);
    }
    // hist[p][h][b] = END offset of bin b (within the half)

    // ---- own-half moments: 8 lanes per segment (contiguous eighths) ----
    {
        const int s  = lane >> 3;           // segment 0..7
        const int ee = lane & 7;            // eighth 0..7
        const int beg0 = (s == 0) ? 0 : hist[p][h][16 * s - 1];
        const int end0 = hist[p][h][16 * s + 15];
        const int len  = end0 - beg0;
        const int beg  = beg0 + (len * ee) / 8;
        const int end  = beg0 + (len * (ee + 1)) / 8;
        const float cs = kmn + (s + 0.5f) * segw;

        float m0=0.f,m1=0.f,m2=0.f,m3=0.f,m4=0.f,m5=0.f,m6=0.f,m7=0.f,m8=0.f,m9=0.f,m10=0.f;
        float q0=0.f,q1=0.f,q2=0.f,q3=0.f,q4=0.f,q5=0.f,q6=0.f,q7=0.f,q8=0.f,q9=0.f,q10=0.f;
        for (int e = beg; e < end; ++e) {
            const float2 kv = skv[p][h * 128 + e];
            const float dk = kv.x - cs;
            const float vv = kv.y;
            const float p1 = dk,      p2 = p1 * dk, p3 = p2 * dk, p4 = p3 * dk;
            const float p5 = p4 * dk, p6 = p5 * dk, p7 = p6 * dk, p8 = p7 * dk;
            const float p9 = p8 * dk, pA = p9 * dk;
            m0 += 1.f; m1 += p1; m2 += p2; m3 += p3; m4 += p4; m5 += p5;
            m6 += p6;  m7 += p7; m8 += p8; m9 += p9; m10 += pA;
            q0 += vv;
            q1 = fmaf(vv, p1, q1); q2 = fmaf(vv, p2, q2); q3 = fmaf(vv, p3, q3);
            q4 = fmaf(vv, p4, q4); q5 = fmaf(vv, p5, q5); q6 = fmaf(vv, p6, q6);
            q7 = fmaf(vv, p7, q7); q8 = fmaf(vv, p8, q8); q9 = fmaf(vv, p9, q9);
            q10 = fmaf(vv, pA, q10);
        }
        #pragma unroll
        for (int off = 1; off <= 4; off <<= 1) {
            m0 += __shfl_xor(m0, off); m1 += __shfl_xor(m1, off);
            m2 += __shfl_xor(m2, off); m3 += __shfl_xor(m3, off);
            m4 += __shfl_xor(m4, off); m5 += __shfl_xor(m5, off);
            m6 += __shfl_xor(m6, off); m7 += __shfl_xor(m7, off);
            m8 += __shfl_xor(m8, off); m9 += __shfl_xor(m9, off);
            m10 += __shfl_xor(m10, off);
            q0 += __shfl_xor(q0, off); q1 += __shfl_xor(q1, off);
            q2 += __shfl_xor(q2, off); q3 += __shfl_xor(q3, off);
            q4 += __shfl_xor(q4, off); q5 += __shfl_xor(q5, off);
            q6 += __shfl_xor(q6, off); q7 += __shfl_xor(q7, off);
            q8 += __shfl_xor(q8, off); q9 += __shfl_xor(q9, off);
            q10 += __shfl_xor(q10, off);
        }
        float4 wv4;
        bool doW = true;
        if (ee == 0)      wv4 = make_float4(m0, m1, m2 * 0.5f, m3 * (1.f/6.f));
        else if (ee == 1) wv4 = make_float4(m4 * (1.f/24.f), m5 * (1.f/120.f),
                                            m6 * (1.f/720.f), m7 * (1.f/5040.f));
        else if (ee == 2) wv4 = make_float4(m8 * (1.f/40320.f), m9 * (1.f/362880.f),
                                            m10 * (1.f/3628800.f), 0.f);
        else if (ee == 3) wv4 = make_float4(q0, q1, q2 * 0.5f, q3 * (1.f/6.f));
        else if (ee == 4) wv4 = make_float4(q4 * (1.f/24.f), q5 * (1.f/120.f),
                                            q6 * (1.f/720.f), q7 * (1.f/5040.f));
        else if (ee == 5) wv4 = make_float4(q8 * (1.f/40320.f), q9 * (1.f/362880.f),
                                            q10 * (1.f/3628800.f), 0.f);
        else doW = false;
        if (doW)
            *reinterpret_cast<float4*>(&momH[p][h][s][ee * 4]) = wv4;
    }
    __syncthreads();   // barrier 3: both halves' moments visible

    // ---- row loop: 2 rows/lane, coeffs = halfA + halfB summed inline ----
    const v2f u = {a0 * LN2, a1 * LN2};
    const float c0s = kmn + 0.5f * segw;

    v2f Ee, gg;
    Ee.x = __builtin_amdgcn_exp2f(a0 * c0s);
    Ee.y = __builtin_amdgcn_exp2f(a1 * c0s);
    gg.x = __builtin_amdgcn_exp2f(a0 * segw);
    gg.y = __builtin_amdgcn_exp2f(a1 * segw);
    const v2f G2 = gg * gg;
    v2f Eo = Ee * gg;

    v2f de = {0.f,0.f}, dd = {0.f,0.f}, ne = {0.f,0.f}, no = {0.f,0.f};

    const float4* __restrict__ MA = (const float4*)&momH[p][0][0][0];  // 6/seg
    const float4* __restrict__ MB = (const float4*)&momH[p][1][0][0];

    #pragma unroll 4
    for (int s = 0; s < NSEG; s += 2) {
        {   // even segment
            const float4 a0f = MA[s*6+0], a1f = MA[s*6+1], a2f = MA[s*6+2];
            const float4 a3f = MA[s*6+3], a4f = MA[s*6+4], a5f = MA[s*6+5];
            const float4 b0f = MB[s*6+0], b1f = MB[s*6+1], b2f = MB[s*6+2];
            const float4 b3f = MB[s*6+3], b4f = MB[s*6+4], b5f = MB[s*6+5];
            const float4 f0 = make_float4(a0f.x+b0f.x, a0f.y+b0f.y, a0f.z+b0f.z, a0f.w+b0f.w);
            const float4 f1 = make_float4(a1f.x+b1f.x, a1f.y+b1f.y, a1f.z+b1f.z, a1f.w+b1f.w);
            const float4 f2 = make_float4(a2f.x+b2f.x, a2f.y+b2f.y, a2f.z+b2f.z, a2f.w+b2f.w);
            const float4 f3 = make_float4(a3f.x+b3f.x, a3f.y+b3f.y, a3f.z+b3f.z, a3f.w+b3f.w);
            const float4 f4 = make_float4(a4f.x+b4f.x, a4f.y+b4f.y, a4f.z+b4f.z, a4f.w+b4f.w);
            const float4 f5 = make_float4(a5f.x+b5f.x, a5f.y+b5f.y, a5f.z+b5f.z, a5f.w+b5f.w);
            const v2f hd = horner10(u, f0, f1, f2);
            const v2f hn = horner10(u, f3, f4, f5);
            de = __builtin_elementwise_fma(Ee, hd, de);
            ne = __builtin_elementwise_fma(Ee, hn, ne);
            Ee = Ee * G2;
        }
        {   // odd segment
            const int so = s + 1;
            const float4 a0f = MA[so*6+0], a1f = MA[so*6+1], a2f = MA[so*6+2];
            const float4 a3f = MA[so*6+3], a4f = MA[so*6+4], a5f = MA[so*6+5];
            const float4 b0f = MB[so*6+0], b1f = MB[so*6+1], b2f = MB[so*6+2];
            const float4 b3f = MB[so*6+3], b4f = MB[so*6+4], b5f = MB[so*6+5];
            const float4 f0 = make_float4(a0f.x+b0f.x, a0f.y+b0f.y, a0f.z+b0f.z, a0f.w+b0f.w);
            const float4 f1 = make_float4(a1f.x+b1f.x, a1f.y+b1f.y, a1f.z+b1f.z, a1f.w+b1f.w);
            const float4 f2 = make_float4(a2f.x+b2f.x, a2f.y+b2f.y, a2f.z+b2f.z, a2f.w+b2f.w);
            const float4 f3 = make_float4(a3f.x+b3f.x, a3f.y+b3f.y, a3f.z+b3f.z, a3f.w+b3f.w);
            const float4 f4 = make_float4(a4f.x+b4f.x, a4f.y+b4f.y, a4f.z+b4f.z, a4f.w+b4f.w);
            const float4 f5 = make_float4(a5f.x+b5f.x, a5f.y+b5f.y, a5f.z+b5f.z, a5f.w+b5f.w);
            const v2f hd = horner10(u, f0, f1, f2);
            const v2f hn = horner10(u, f3, f4, f5);
            dd = __builtin_elementwise_fma(Eo, hd, dd);
            no = __builtin_elementwise_fma(Eo, hn, no);
            Eo = Eo * G2;
        }
    }

    const v2f den = de + dd;
    const v2f num = ne + no;

    const float wo = opw[0], bo = opb[0];
    const int n  = n0 + p;
    const int r0 = blk * BSZ + h * 128 + 2 * lane;
    out[(size_t)(r0 + 0) * NN + n] = fmaf(num.x / den.x, wo, bo);
    out[(size_t)(r0 + 1) * NN + n] = fmaf(num.y / den.y, wo, bo);
}

extern "C" void kernel_launch(void* const* d_in, const int* in_sizes, int n_in,
                              void* d_out, int out_size, void* d_ws, size_t ws_size,
                              hipStream_t stream) {
    const float* q   = (const float*)d_in[0];
    const float* k   = (const float*)d_in[1];
    const float* v   = (const float*)d_in[2];
    const float* ipw = (const float*)d_in[3];
    const float* ipb = (const float*)d_in[4];
    const float* opw = (const float*)d_in[5];
    const float* opb = (const float*)d_in[6];
    float* out = (float*)d_out;

    // 2048 WGs x 256 threads: WG = (blk, n0..n0+1), 2 waves per problem.
    BlockCrossAttn_kernel<<<dim3(NBLK * NN / 2), dim3(256), 0, stream>>>(
        q, k, v, ipw, ipb, opw, opb, out);
}

// Round 32
// 17.779 us; speedup vs baseline: 1.4912x; 1.4912x over previous
//
#include <hip/hip_runtime.h>

// L=32768, N=32, E=H=1, BS=256 -> 4096 rank-1 softmax problems:
//   out_i = sum_j 2^(a'_i k_j) v_j / sum_j 2^(a'_i k_j),  a' = (wq q + bq) log2e.
// No max-subtraction (f32-safe, scale-invariant; validated R5-R31).
//
// R32 = exact revert to R30 (17.8us best). R31's 2-wave split regressed 50%
// (barrier re-serialization + doubled LDS pipeline traffic), completing the
// 7-experiment proof that the decoupled one-wave-per-problem pipeline is the
// optimal organization. R30 structure: one WG = 4 waves = 4 problems
// (blk, n0..n0+3); cooperative coalesced staging + projection + LDS
// transpose; ONE barrier; then per-wave private sort -> segmented-Taylor
// moments (NSEG=8, deg-10) -> E-recurrence Horner row loop.

#define LL    32768
#define NN    32
#define BSZ   256
#define NBLK  (LL / BSZ)
#define NSEG  8
#define LOG2E 1.4426950408889634f
#define LN2   0.6931471805599453f

typedef float v2f __attribute__((ext_vector_type(2)));

// deg-10 Horner: coefficients c0..c10 = {f0.xyzw, f1.xyzw, f2.xyz}
__device__ __forceinline__ v2f horner10(v2f u, float4 f0, float4 f1, float4 f2) {
    v2f h = {f2.z, f2.z};
    h = __builtin_elementwise_fma(h, u, (v2f){f2.y, f2.y});
    h = __builtin_elementwise_fma(h, u, (v2f){f2.x, f2.x});
    h = __builtin_elementwise_fma(h, u, (v2f){f1.w, f1.w});
    h = __builtin_elementwise_fma(h, u, (v2f){f1.z, f1.z});
    h = __builtin_elementwise_fma(h, u, (v2f){f1.y, f1.y});
    h = __builtin_elementwise_fma(h, u, (v2f){f1.x, f1.x});
    h = __builtin_elementwise_fma(h, u, (v2f){f0.w, f0.w});
    h = __builtin_elementwise_fma(h, u, (v2f){f0.z, f0.z});
    h = __builtin_elementwise_fma(h, u, (v2f){f0.y, f0.y});
    h = __builtin_elementwise_fma(h, u, (v2f){f0.x, f0.x});
    return h;
}

__global__ __launch_bounds__(256) void BlockCrossAttn_kernel(
    const float* __restrict__ q_in, const float* __restrict__ k_in,
    const float* __restrict__ v_in,
    const float* __restrict__ ipw,  const float* __restrict__ ipb,
    const float* __restrict__ opw,  const float* __restrict__ opb,
    float* __restrict__ out)
{
    const int t    = threadIdx.x;        // 0..255
    const int lane = t & 63;
    const int w    = t >> 6;             // wave 0..3 -> problem (blk, n0+w)
    const int g    = blockIdx.x;         // 0..1023
    const int blk  = g & 127;            // XCD-aware: siblings same XCD
    const int n0   = (g >> 7) << 2;      // 0,4,...,28

    __shared__ alignas(16) float  sA[4][BSZ];     // staged, transposed [j][row]
    __shared__ alignas(16) float  sK[4][BSZ];
    __shared__ alignas(16) float  sV[4][BSZ];
    __shared__ alignas(16) float2 skv[4][BSZ];    // per-wave sorted (k,v)
    __shared__ alignas(16) float  mom[4][NSEG][24];
    __shared__ int hist[4][128];

    // ---- cooperative staging: thread t = row t, 4 batches n0..n0+3 ----
    {
        const float wq = ipw[0], wk = ipw[1], wv = ipw[2];
        const float bq = ipb[0], bk = ipb[1], bv = ipb[2];
        const int f = (blk * BSZ + t) * NN + n0;       // 16B aligned
        const float4 q4 = *reinterpret_cast<const float4*>(q_in + f);
        const float4 k4 = *reinterpret_cast<const float4*>(k_in + f);
        const float4 v4 = *reinterpret_cast<const float4*>(v_in + f);
        sA[0][t] = fmaf(q4.x, wq, bq) * LOG2E;
        sA[1][t] = fmaf(q4.y, wq, bq) * LOG2E;
        sA[2][t] = fmaf(q4.z, wq, bq) * LOG2E;
        sA[3][t] = fmaf(q4.w, wq, bq) * LOG2E;
        sK[0][t] = fmaf(k4.x, wk, bk);
        sK[1][t] = fmaf(k4.y, wk, bk);
        sK[2][t] = fmaf(k4.z, wk, bk);
        sK[3][t] = fmaf(k4.w, wk, bk);
        sV[0][t] = fmaf(v4.x, wv, bv);
        sV[1][t] = fmaf(v4.y, wv, bv);
        sV[2][t] = fmaf(v4.z, wv, bv);
        sV[3][t] = fmaf(v4.w, wv, bv);
    }
    __syncthreads();   // ONLY barrier: staging -> per-wave private pipelines

    // ---- per-wave private from here (zero further barriers) ----
    const float4 af = *reinterpret_cast<const float4*>(&sA[w][4 * lane]);
    const float4 kf = *reinterpret_cast<const float4*>(&sK[w][4 * lane]);
    const float4 vf = *reinterpret_cast<const float4*>(&sV[w][4 * lane]);
    float kr[4] = {kf.x, kf.y, kf.z, kf.w};
    float vr[4] = {vf.x, vf.y, vf.z, vf.w};

    // wave kmin/kmax
    float kmn = fminf(fminf(kr[0], kr[1]), fminf(kr[2], kr[3]));
    float kmx = fmaxf(fmaxf(kr[0], kr[1]), fmaxf(kr[2], kr[3]));
    #pragma unroll
    for (int off = 32; off >= 1; off >>= 1) {
        kmn = fminf(kmn, __shfl_xor(kmn, off));
        kmx = fmaxf(kmx, __shfl_xor(kmx, off));
    }
    const float rng  = kmx - kmn;
    const float binv = (rng > 0.f) ? (127.99f / rng) : 0.f;
    const float segw = rng * (1.0f / NSEG);

    // ---- counting sort by 7-bit quantized k (wave-private, no barriers) ----
    hist[w][lane]      = 0;
    hist[w][lane + 64] = 0;

    int bin[4];
    #pragma unroll
    for (int r = 0; r < 4; ++r) {
        int b = (int)((kr[r] - kmn) * binv);
        bin[r] = (b < 0) ? 0 : ((b > 127) ? 127 : b);
        atomicAdd(&hist[w][bin[r]], 1);   // wave-private, lane-ordered
    }

    {
        const int c0 = hist[w][lane];
        const int c1 = hist[w][lane + 64];
        int i0 = c0, i1 = c1;
        #pragma unroll
        for (int off = 1; off <= 32; off <<= 1) {
            const int t0 = __shfl_up(i0, off);
            const int t1 = __shfl_up(i1, off);
            if (lane >= off) { i0 += t0; i1 += t1; }
        }
        const int tot0 = __shfl(i0, 63);
        hist[w][lane]      = i0 - c0;     // exclusive starts
        hist[w][lane + 64] = i1 - c1 + tot0;
    }

    #pragma unroll
    for (int r = 0; r < 4; ++r) {
        const int slot = atomicAdd(&hist[w][bin[r]], 1);
        skv[w][slot] = make_float2(kr[r], vr[r]);
    }
    // hist[w][b] = END offset of bin b

    // ---- moments: 8 lanes per segment (contiguous eighth-ranges) ----
    {
        const int s  = lane >> 3;           // segment 0..7
        const int ee = lane & 7;            // eighth 0..7
        const int beg0 = (s == 0) ? 0 : hist[w][16 * s - 1];
        const int end0 = hist[w][16 * s + 15];
        const int len  = end0 - beg0;
        const int beg  = beg0 + (len * ee) / 8;
        const int end  = beg0 + (len * (ee + 1)) / 8;
        const float cs = kmn + (s + 0.5f) * segw;

        float m0=0.f,m1=0.f,m2=0.f,m3=0.f,m4=0.f,m5=0.f,m6=0.f,m7=0.f,m8=0.f,m9=0.f,m10=0.f;
        float q0=0.f,q1=0.f,q2=0.f,q3=0.f,q4=0.f,q5=0.f,q6=0.f,q7=0.f,q8=0.f,q9=0.f,q10=0.f;
        for (int e = beg; e < end; ++e) {
            const float2 kv = skv[w][e];
            const float dk = kv.x - cs;
            const float vv = kv.y;
            const float p1 = dk,      p2 = p1 * dk, p3 = p2 * dk, p4 = p3 * dk;
            const float p5 = p4 * dk, p6 = p5 * dk, p7 = p6 * dk, p8 = p7 * dk;
            const float p9 = p8 * dk, pA = p9 * dk;
            m0 += 1.f; m1 += p1; m2 += p2; m3 += p3; m4 += p4; m5 += p5;
            m6 += p6;  m7 += p7; m8 += p8; m9 += p9; m10 += pA;
            q0 += vv;
            q1 = fmaf(vv, p1, q1); q2 = fmaf(vv, p2, q2); q3 = fmaf(vv, p3, q3);
            q4 = fmaf(vv, p4, q4); q5 = fmaf(vv, p5, q5); q6 = fmaf(vv, p6, q6);
            q7 = fmaf(vv, p7, q7); q8 = fmaf(vv, p8, q8); q9 = fmaf(vv, p9, q9);
            q10 = fmaf(vv, pA, q10);
        }
        // combine 8 eighths (aligned 8-lane groups)
        #pragma unroll
        for (int off = 1; off <= 4; off <<= 1) {
            m0 += __shfl_xor(m0, off); m1 += __shfl_xor(m1, off);
            m2 += __shfl_xor(m2, off); m3 += __shfl_xor(m3, off);
            m4 += __shfl_xor(m4, off); m5 += __shfl_xor(m5, off);
            m6 += __shfl_xor(m6, off); m7 += __shfl_xor(m7, off);
            m8 += __shfl_xor(m8, off); m9 += __shfl_xor(m9, off);
            m10 += __shfl_xor(m10, off);
            q0 += __shfl_xor(q0, off); q1 += __shfl_xor(q1, off);
            q2 += __shfl_xor(q2, off); q3 += __shfl_xor(q3, off);
            q4 += __shfl_xor(q4, off); q5 += __shfl_xor(q5, off);
            q6 += __shfl_xor(q6, off); q7 += __shfl_xor(q7, off);
            q8 += __shfl_xor(q8, off); q9 += __shfl_xor(q9, off);
            q10 += __shfl_xor(q10, off);
        }
        // 6 float4 per segment, written by lanes ee=0..5
        float4 wv4;
        bool doW = true;
        if (ee == 0)      wv4 = make_float4(m0, m1, m2 * 0.5f, m3 * (1.f/6.f));
        else if (ee == 1) wv4 = make_float4(m4 * (1.f/24.f), m5 * (1.f/120.f),
                                            m6 * (1.f/720.f), m7 * (1.f/5040.f));
        else if (ee == 2) wv4 = make_float4(m8 * (1.f/40320.f), m9 * (1.f/362880.f),
                                            m10 * (1.f/3628800.f), 0.f);
        else if (ee == 3) wv4 = make_float4(q0, q1, q2 * 0.5f, q3 * (1.f/6.f));
        else if (ee == 4) wv4 = make_float4(q4 * (1.f/24.f), q5 * (1.f/120.f),
                                            q6 * (1.f/720.f), q7 * (1.f/5040.f));
        else if (ee == 5) wv4 = make_float4(q8 * (1.f/40320.f), q9 * (1.f/362880.f),
                                            q10 * (1.f/3628800.f), 0.f);
        else doW = false;
        if (doW)
            *reinterpret_cast<float4*>(&mom[w][s][ee * 4]) = wv4;
    }

    // ---- row loop: 4 rows/thread, E-recurrence (2 chains), deg-10 Horner ----
    const float a[4] = {af.x, af.y, af.z, af.w};   // already * LOG2E
    const v2f u01 = {a[0] * LN2, a[1] * LN2};
    const v2f u23 = {a[2] * LN2, a[3] * LN2};
    const float c0s = kmn + 0.5f * segw;

    v2f Ee01, Ee23, g01, g23;
    Ee01.x = __builtin_amdgcn_exp2f(a[0] * c0s);
    Ee01.y = __builtin_amdgcn_exp2f(a[1] * c0s);
    Ee23.x = __builtin_amdgcn_exp2f(a[2] * c0s);
    Ee23.y = __builtin_amdgcn_exp2f(a[3] * c0s);
    g01.x  = __builtin_amdgcn_exp2f(a[0] * segw);
    g01.y  = __builtin_amdgcn_exp2f(a[1] * segw);
    g23.x  = __builtin_amdgcn_exp2f(a[2] * segw);
    g23.y  = __builtin_amdgcn_exp2f(a[3] * segw);
    const v2f G2_01 = g01 * g01;
    const v2f G2_23 = g23 * g23;
    v2f Eo01 = Ee01 * g01;
    v2f Eo23 = Ee23 * g23;

    v2f de01 = {0.f,0.f}, do01 = {0.f,0.f}, de23 = {0.f,0.f}, do23 = {0.f,0.f};
    v2f ne01 = {0.f,0.f}, no01 = {0.f,0.f}, ne23 = {0.f,0.f}, no23 = {0.f,0.f};

    const float4* __restrict__ M4 = (const float4*)&mom[w][0][0];  // 6 per seg

    #pragma unroll 4
    for (int s = 0; s < NSEG; s += 2) {
        {   // even segment
            const float4 f0 = M4[s * 6 + 0];
            const float4 f1 = M4[s * 6 + 1];
            const float4 f2 = M4[s * 6 + 2];
            const float4 f3 = M4[s * 6 + 3];
            const float4 f4 = M4[s * 6 + 4];
            const float4 f5 = M4[s * 6 + 5];
            const v2f hd01 = horner10(u01, f0, f1, f2);
            const v2f hn01 = horner10(u01, f3, f4, f5);
            const v2f hd23 = horner10(u23, f0, f1, f2);
            const v2f hn23 = horner10(u23, f3, f4, f5);
            de01 = __builtin_elementwise_fma(Ee01, hd01, de01);
            ne01 = __builtin_elementwise_fma(Ee01, hn01, ne01);
            de23 = __builtin_elementwise_fma(Ee23, hd23, de23);
            ne23 = __builtin_elementwise_fma(Ee23, hn23, ne23);
            Ee01 = Ee01 * G2_01;
            Ee23 = Ee23 * G2_23;
        }
        {   // odd segment
            const float4 f0 = M4[(s + 1) * 6 + 0];
            const float4 f1 = M4[(s + 1) * 6 + 1];
            const float4 f2 = M4[(s + 1) * 6 + 2];
            const float4 f3 = M4[(s + 1) * 6 + 3];
            const float4 f4 = M4[(s + 1) * 6 + 4];
            const float4 f5 = M4[(s + 1) * 6 + 5];
            const v2f hd01 = horner10(u01, f0, f1, f2);
            const v2f hn01 = horner10(u01, f3, f4, f5);
            const v2f hd23 = horner10(u23, f0, f1, f2);
            const v2f hn23 = horner10(u23, f3, f4, f5);
            do01 = __builtin_elementwise_fma(Eo01, hd01, do01);
            no01 = __builtin_elementwise_fma(Eo01, hn01, no01);
            do23 = __builtin_elementwise_fma(Eo23, hd23, do23);
            no23 = __builtin_elementwise_fma(Eo23, hn23, no23);
            Eo01 = Eo01 * G2_01;
            Eo23 = Eo23 * G2_23;
        }
    }

    const v2f den01 = de01 + do01, den23 = de23 + do23;
    const v2f num01 = ne01 + no01, num23 = ne23 + no23;

    const float wo = opw[0], bo = opb[0];
    const int n = n0 + w;
    const int rbase = blk * BSZ + 4 * lane;
    out[(size_t)(rbase + 0) * NN + n] = fmaf(num01.x / den01.x, wo, bo);
    out[(size_t)(rbase + 1) * NN + n] = fmaf(num01.y / den01.y, wo, bo);
    out[(size_t)(rbase + 2) * NN + n] = fmaf(num23.x / den23.x, wo, bo);
    out[(size_t)(rbase + 3) * NN + n] = fmaf(num23.y / den23.y, wo, bo);
}

extern "C" void kernel_launch(void* const* d_in, const int* in_sizes, int n_in,
                              void* d_out, int out_size, void* d_ws, size_t ws_size,
                              hipStream_t stream) {
    const float* q   = (const float*)d_in[0];
    const float* k   = (const float*)d_in[1];
    const float* v   = (const float*)d_in[2];
    const float* ipw = (const float*)d_in[3];
    const float* ipb = (const float*)d_in[4];
    const float* opw = (const float*)d_in[5];
    const float* opb = (const float*)d_in[6];
    float* out = (float*)d_out;

    // 1024 WGs x 256 threads: WG = (blk, n0..n0+3), one wave per problem.
    BlockCrossAttn_kernel<<<dim3(NBLK * NN / 4), dim3(256), 0, stream>>>(
        q, k, v, ipw, ipb, opw, opb, out);
}